// Round 4
// baseline (314.864 us; speedup 1.0000x reference)
//
#include <hip/hip_runtime.h>
#include <hip/hip_bf16.h>

typedef __bf16 bf16_t;
typedef __bf16 bf16x8 __attribute__((ext_vector_type(8)));
typedef float f32x16 __attribute__((ext_vector_type(16)));
typedef float f32x4v __attribute__((ext_vector_type(4)));

#define NB 32
#define CIN 128
#define HIN 64
#define WIN 64
#define OCH 256
#define OHW 62

// ---------------------------------------------------------------------------
// Pre-kernel: weights fp32 [256][128][3][3] -> bf16 wt[tap][o][c], c fast.
// Thread owns 8 consecutive c -> one 16B bf16x8 write (fully coalesced).
// ---------------------------------------------------------------------------
__global__ __launch_bounds__(256) void conv_wt_kernel(const float* __restrict__ w,
                                                      bf16_t* __restrict__ wt) {
  int t = blockIdx.x * 256 + threadIdx.x;   // 36864 threads total
  int c8 = t & 15;                          // c-octet 0..15
  int o = (t >> 4) & 255;
  int tap = t >> 12;                        // 0..8
  const float* src = w + (size_t)o * 1152 + (size_t)c8 * 72 + tap;  // c*9 stride
  bf16x8 v;
#pragma unroll
  for (int k = 0; k < 8; ++k) v[k] = (bf16_t)src[k * 9];
  *(bf16x8*)(wt + (size_t)tap * 32768 + o * 128 + c8 * 8) = v;
}

// ---------------------------------------------------------------------------
// Main: fused convert+transpose+implicit-GEMM, barrier-free main loop.
// Block = (b, i0=2*bx): out tile 256o x (2i x 64j). 512 thr = 8 waves,
// wave w owns o-panel [32w, 32w+32) x all 128 pos (zero W duplication).
// x slab: fp32 global -> reg cvt -> bf16 LDS [256 rows=(4h x 64w)][256B=128c],
// XOR-swizzled key=(row&15)<<4 -> B-frag ds_read_b128 is 2-way (free).
// Staged ONCE -> single __syncthreads in the kernel.
// W: direct global(L2)->reg, tap-level ping-pong prefetch (a0/a1, static idx).
// MFMA: 32x32x16 bf16. C/D: col=lane&31 (pos), row=(r&3)+8*(r>>2)+4*(lane>>5) (o).
// Rows that would spill past the slab (j+kw>=64 at h_loc=3) are clamped to 255:
// in-bounds garbage feeding ONLY masked output columns (j>=62).
// ---------------------------------------------------------------------------
__global__ __launch_bounds__(512) void conv_main_kernel(const float* __restrict__ x,
                                                        const bf16_t* __restrict__ wt,
                                                        float* __restrict__ out) {
  __shared__ __align__(16) char xs[256 * 256];   // 65,536 B exactly

  const int tid = threadIdx.x;
  const int lane = tid & 63;
  const int l31 = lane & 31;
  const int lhi = lane >> 5;             // 0/1 (k-half)
  const int wid = tid >> 6;              // 0..7
  const int o_base = wid * 32;
  const int b = blockIdx.y;
  const int i0 = blockIdx.x * 2;

  // staging mapping: thread -> (c-octet, w-quad, h); two passes cover c 0..127
  const int c8 = tid & 7;                // c-octet within a 64c half
  const int w0 = ((tid >> 3) & 15) * 4;  // w 0..60 step 4
  const int hh = tid >> 7;               // 0..3
  const float* xbase = x + (((size_t)b * CIN) * HIN + (i0 + hh)) * WIN + w0;

  // W fragment base (bytes): wt[tap][o][128c]; frag(tap,kk) at
  // wb + tap*65536 + kk*32 ; lane covers o = o_base+l31, k-half lhi
  const char* wb = (const char*)wt + (o_base + l31) * 256 + lhi * 16;

  f32x16 acc[4];
#pragma unroll
  for (int n = 0; n < 4; ++n)
#pragma unroll
    for (int r = 0; r < 16; ++r) acc[n][r] = 0.f;

#define STAGE_LOAD(xr, p)                                                      \
  {                                                                            \
    _Pragma("unroll") for (int dc = 0; dc < 8; ++dc)                           \
        xr[dc] = *(const f32x4v*)(xbase +                                      \
                                  (size_t)((p) * 64 + c8 * 8 + dc) * 4096);    \
  }

#define STAGE_WRITE(xr, p)                                                     \
  {                                                                            \
    _Pragma("unroll") for (int dw = 0; dw < 4; ++dw) {                         \
      bf16x8 v;                                                                \
      _Pragma("unroll") for (int dc = 0; dc < 8; ++dc)                         \
          v[dc] = (bf16_t)xr[dc][dw];                                          \
      int row = hh * 64 + w0 + dw;                                             \
      *(bf16x8*)(xs + row * 256 +                                              \
                 (((p) * 128 + c8 * 16) ^ ((row & 15) << 4))) = v;             \
    }                                                                          \
  }

#define LOAD_A(dst, s)                                                         \
  {                                                                            \
    const char* p_ = wb + (s) * 65536;                                         \
    _Pragma("unroll") for (int kk = 0; kk < 8; ++kk)                           \
        dst[kk] = *(const bf16x8*)(p_ + kk * 32);                              \
  }

#define STEP_MFMA(a, s)                                                        \
  {                                                                            \
    const int kh_ = (s) / 3, kw_ = (s) % 3;                                    \
    _Pragma("unroll") for (int n = 0; n < 4; ++n) {                            \
      int row = ((n >> 1) + kh_) * 64 + (n & 1) * 32 + l31 + kw_;              \
      row = row < 256 ? row : 255;   /* in-bounds garbage, masked cols only */ \
      _Pragma("unroll") for (int kk = 0; kk < 8; ++kk) {                       \
        bf16x8 bb = *(const bf16x8*)(                                          \
            xs + row * 256 + ((kk * 32 + lhi * 16) ^ ((row & 15) << 4)));      \
        acc[n] = __builtin_amdgcn_mfma_f32_32x32x16_bf16(a[kk], bb, acc[n],    \
                                                         0, 0, 0);             \
      }                                                                        \
    }                                                                          \
  }

  // ---- prologue: stage the full 4h x 64w x 128c slab (once) ----
  {
    f32x4v xr0[8], xr1[8];
    STAGE_LOAD(xr0, 0);
    STAGE_LOAD(xr1, 1);
    STAGE_WRITE(xr0, 0);
    STAGE_WRITE(xr1, 1);
  }
  __syncthreads();   // the only barrier

  // ---- 9 taps, barrier-free; W ping-pong prefetch one tap ahead ----
  bf16x8 a0[8], a1[8];
  LOAD_A(a0, 0);
#pragma unroll
  for (int s2 = 0; s2 < 4; ++s2) {
    LOAD_A(a1, 2 * s2 + 1);
    STEP_MFMA(a0, 2 * s2);
    LOAD_A(a0, 2 * s2 + 2);
    STEP_MFMA(a1, 2 * s2 + 1);
  }
  STEP_MFMA(a0, 8);

  // ---- epilogue: scatter acc to out[b][o][i][j]; j-contiguous across lanes ----
#pragma unroll
  for (int n = 0; n < 4; ++n) {
    int pos = n * 32 + l31;
    int j = pos & 63;
    int i = i0 + (pos >> 6);
    if (j < 62) {
#pragma unroll
      for (int r = 0; r < 16; ++r) {
        int o = o_base + (r & 3) + 8 * (r >> 2) + 4 * lhi;
        out[((size_t)(b * 256 + o) * OHW + i) * OHW + j] = acc[n][r];
      }
    }
  }
#undef STAGE_LOAD
#undef STAGE_WRITE
#undef LOAD_A
#undef STEP_MFMA
}

// ---------------------------------------------------------------------------
extern "C" void kernel_launch(void* const* d_in, const int* in_sizes, int n_in,
                              void* d_out, int out_size, void* d_ws, size_t ws_size,
                              hipStream_t stream) {
  const float* x = (const float*)d_in[0];
  const float* w = (const float*)d_in[1];
  float* out = (float*)d_out;

  bf16_t* wt = (bf16_t*)d_ws;   // 9*256*128*2 = 589,824 B

  conv_wt_kernel<<<dim3(144), dim3(256), 0, stream>>>(w, wt);
  conv_main_kernel<<<dim3(31, NB), dim3(512), 0, stream>>>(x, wt, out);
}

// Round 6
// 258.252 us; speedup vs baseline: 1.2192x; 1.2192x over previous
//
#include <hip/hip_runtime.h>
#include <hip/hip_bf16.h>

typedef __bf16 bf16_t;
typedef __bf16 bf16x8 __attribute__((ext_vector_type(8)));
typedef float f32x16 __attribute__((ext_vector_type(16)));
typedef float f32x4v __attribute__((ext_vector_type(4)));

#define NB 32
#define CIN 128
#define HIN 64
#define WIN 64
#define OCH 256
#define OHW 62

// ---------------------------------------------------------------------------
// Pre-kernel: weights fp32 [256][128][3][3] -> bf16 wt2, fragment-major:
// wt2 frag index t = ((tap*8 + o5)*8 + kk)*64 + lane, each 16 B.
// frag(t) holds W[o = o5*32 + (lane&31)][c = kk*16 + (lane>>5)*8 .. +7] at tap.
// => one wave A-fragment load = contiguous 1024 B (perfectly coalesced).
// ---------------------------------------------------------------------------
__global__ __launch_bounds__(256) void conv_wt_kernel(const float* __restrict__ w,
                                                      bf16_t* __restrict__ wt2) {
  int t = blockIdx.x * 256 + threadIdx.x;   // 36864 frags
  int lane = t & 63;
  int kk = (t >> 6) & 7;
  int o5 = (t >> 9) & 7;
  int tap = t >> 12;
  int o = o5 * 32 + (lane & 31);
  int c0 = kk * 16 + (lane >> 5) * 8;
  const float* src = w + (size_t)o * 1152 + (size_t)c0 * 9 + tap;  // c-stride 9
  bf16x8 v;
#pragma unroll
  for (int e = 0; e < 8; ++e) v[e] = (bf16_t)src[e * 9];
  *(bf16x8*)(wt2 + (size_t)t * 8) = v;
}

// ---------------------------------------------------------------------------
// Main: fused convert+transpose+implicit-GEMM, m=2 n=4 operand reuse.
// Block (256 thr = 4 waves) = (b, i0=2*bx): out tile 256o x (2i x 64j).
// Wave wid owns o-panel [64*wid, 64*wid+64) (m=2 sub-tiles of 32o) x all
// 128 pos (n=4). acc[m2][n4] f32x16 = 128 VGPR.
// x slab: fp32 global -> reg cvt -> bf16 LDS [256 rows=(4h x 64w)][256B=128c],
// XOR swizzle key=(row&15)<<4 (measured 0 bank conflicts in r4). Staged once,
// ONE barrier. 64 KB LDS + <=256 VGPR => 2 blocks/CU resident.
// W: coalesced 1024B fragment loads from L2, half-tap ping-pong (A0/A1).
// kk-outer MFMA order: 8 independent MFMAs per kk step (acc-chain distance 8).
// MFMA 32x32x16: A lane&31=o-row, B lane&31=pos-col, k-half=lane>>5.
// C/D: col(pos)=lane&31, row(o)=(r&3)+8*(r>>2)+4*(lane>>5).
// ---------------------------------------------------------------------------
__global__ __launch_bounds__(256, 2) void conv_main_kernel(const float* __restrict__ x,
                                                           const bf16_t* __restrict__ wt2,
                                                           float* __restrict__ out) {
  __shared__ __align__(16) char xs[256 * 256];   // 65,536 B

  const int tid = threadIdx.x;
  const int lane = tid & 63;
  const int l31 = lane & 31;
  const int lhi = lane >> 5;
  const int wid = tid >> 6;              // 0..3
  const int b = blockIdx.y;
  const int i0 = blockIdx.x * 2;

  const char* wt2b = (const char*)wt2;

  f32x16 acc[2][4];
#pragma unroll
  for (int m = 0; m < 2; ++m)
#pragma unroll
    for (int n = 0; n < 4; ++n)
#pragma unroll
      for (int r = 0; r < 16; ++r) acc[m][n][r] = 0.f;

  // ---- stage x slab: rows i0..i0+3 (all exist: i0<=60 -> i0+3<=63),
  //      64 w, 128 c. thread = (c8=tid&7, wq=(tid>>3)&15, r=tid>>7). ----
  {
    const int c8 = tid & 7;
    const int wq = (tid >> 3) & 15;
    const int rr = tid >> 7;             // 0..1
#pragma unroll
    for (int hp = 0; hp < 2; ++hp) {
#pragma unroll
      for (int cp = 0; cp < 2; ++cp) {
        const int h_loc = hp * 2 + rr;
        const float* src = x + (((size_t)b * CIN + cp * 64 + c8 * 8) * HIN +
                                (i0 + h_loc)) * WIN + wq * 4;
        f32x4v xr[8];
#pragma unroll
        for (int dc = 0; dc < 8; ++dc)
          xr[dc] = *(const f32x4v*)(src + (size_t)dc * (HIN * WIN));
#pragma unroll
        for (int dw = 0; dw < 4; ++dw) {
          bf16x8 v;
#pragma unroll
          for (int dc = 0; dc < 8; ++dc) v[dc] = (bf16_t)xr[dc][dw];
          int row = h_loc * 64 + wq * 4 + dw;
          *(bf16x8*)(xs + row * 256 +
                     ((cp * 128 + c8 * 16) ^ ((row & 15) << 4))) = v;
        }
      }
    }
  }
  __syncthreads();   // the only barrier

  // A-frag byte address: ((((tap*8 + (wid*2+m))*8 + kk)*64 + lane)*16
#define LOAD_AH(dst, s, half)                                                  \
  {                                                                            \
    _Pragma("unroll") for (int m = 0; m < 2; ++m)                              \
        _Pragma("unroll") for (int kk4 = 0; kk4 < 4; ++kk4)                    \
            dst[m * 4 + kk4] = *(const bf16x8*)(                               \
                wt2b + ((((size_t)(s) * 8 + wid * 2 + m) * 8 + (half) * 4 +    \
                         kk4) * 64 + lane) * 16);                              \
  }

#define COMP(A, s, half)                                                       \
  {                                                                            \
    const int kh_ = (s) / 3, kw_ = (s) % 3;                                    \
    _Pragma("unroll") for (int kk4 = 0; kk4 < 4; ++kk4) {                      \
      bf16x8 bb[4];                                                            \
      _Pragma("unroll") for (int n = 0; n < 4; ++n) {                          \
        int row = ((n >> 1) + kh_) * 64 + (n & 1) * 32 + l31 + kw_;            \
        row = row < 256 ? row : 255;  /* only j>=62 (masked) lanes clamp */    \
        bb[n] = *(const bf16x8*)(                                              \
            xs + row * 256 +                                                   \
            ((((half) * 4 + kk4) * 32 + lhi * 16) ^ ((row & 15) << 4)));       \
      }                                                                        \
      __builtin_amdgcn_s_setprio(1);                                           \
      _Pragma("unroll") for (int n = 0; n < 4; ++n)                            \
          _Pragma("unroll") for (int m = 0; m < 2; ++m)                        \
              acc[m][n] = __builtin_amdgcn_mfma_f32_32x32x16_bf16(             \
                  A[m * 4 + kk4], bb[n], acc[m][n], 0, 0, 0);                  \
      __builtin_amdgcn_s_setprio(0);                                           \
    }                                                                          \
  }

  bf16x8 A0[8], A1[8];
  LOAD_AH(A0, 0, 0);
#pragma unroll
  for (int t = 0; t < 9; ++t) {
    LOAD_AH(A1, t, 1);
    COMP(A0, t, 0);
    if (t < 8) LOAD_AH(A0, t + 1, 0);
    COMP(A1, t, 1);
  }

  // ---- epilogue: out[b][o][i][j] ----
#pragma unroll
  for (int n = 0; n < 4; ++n) {
    int j = (n & 1) * 32 + l31;
    int i = i0 + (n >> 1);
    if (j < 62) {
#pragma unroll
      for (int m = 0; m < 2; ++m) {
#pragma unroll
        for (int r = 0; r < 16; ++r) {
          int o = (wid * 2 + m) * 32 + (r & 3) + 8 * (r >> 2) + 4 * lhi;
          out[((size_t)(b * 256 + o) * OHW + i) * OHW + j] = acc[m][n][r];
        }
      }
    }
  }
#undef LOAD_AH
#undef COMP
}

// ---------------------------------------------------------------------------
extern "C" void kernel_launch(void* const* d_in, const int* in_sizes, int n_in,
                              void* d_out, int out_size, void* d_ws, size_t ws_size,
                              hipStream_t stream) {
  const float* x = (const float*)d_in[0];
  const float* w = (const float*)d_in[1];
  float* out = (float*)d_out;

  bf16_t* wt2 = (bf16_t*)d_ws;   // 36864 * 16 B = 589,824 B

  conv_wt_kernel<<<dim3(144), dim3(256), 0, stream>>>(w, wt2);
  conv_main_kernel<<<dim3(31, NB), dim3(256), 0, stream>>>(x, wt2, out);
}

// Round 9
// 243.513 us; speedup vs baseline: 1.2930x; 1.0605x over previous
//
#include <hip/hip_runtime.h>
#include <hip/hip_bf16.h>

typedef __bf16 bf16_t;
typedef __bf16 bf16x8 __attribute__((ext_vector_type(8)));
typedef float f32x16 __attribute__((ext_vector_type(16)));
typedef float f32x4v __attribute__((ext_vector_type(4)));

#define NB 32
#define CIN 128
#define HIN 64
#define WIN 64
#define OCH 256
#define OHW 62

// ---------------------------------------------------------------------------
// Pre-kernel: weights fp32 [256][128][3][3] -> bf16 wt2, fragment-major:
// frag t = ((tap*8 + o5)*8 + kk)*64 + lane, 16 B each;
// holds W[o = o5*32 + (lane&31)][c = kk*16 + (lane>>5)*8 .. +7] at tap.
// One wave A-fragment load = contiguous 1024 B (perfectly coalesced).
// ---------------------------------------------------------------------------
__global__ __launch_bounds__(256) void conv_wt_kernel(const float* __restrict__ w,
                                                      bf16_t* __restrict__ wt2) {
  int t = blockIdx.x * 256 + threadIdx.x;   // 36864 frags
  int lane = t & 63;
  int kk = (t >> 6) & 7;
  int o5 = (t >> 9) & 7;
  int tap = t >> 12;
  int o = o5 * 32 + (lane & 31);
  int c0 = kk * 16 + (lane >> 5) * 8;
  const float* src = w + (size_t)o * 1152 + (size_t)c0 * 9 + tap;  // c-stride 9
  bf16x8 v;
#pragma unroll
  for (int e = 0; e < 8; ++e) v[e] = (bf16_t)src[e * 9];
  *(bf16x8*)(wt2 + (size_t)t * 8) = v;
}

// ---------------------------------------------------------------------------
// Main: fused convert+transpose+implicit-GEMM, occupancy-first (m=2, n=2).
// Block (256 thr = 4 waves) = (b, i0): out tile 256o x 62j at ONE i-row.
// Wave wid: o-panel [64*wid, 64*wid+64) x all 64 pos. acc[2][2] f32x16
// = 64 AGPR; operands fully ping-ponged (Aa/Ab/Ba/Bb, 64 VGPR).
// x slab: 3h x 64w x 128c bf16 = 48 KB -> 3 blocks/CU (12 waves, 3/SIMD).
// Swizzle key=(row&15)<<4 on 256B rows (0 conflicts measured r4/r6).
// Single stage, ONE barrier; no h-edge cases (i0<=61 -> i0+2<=63).
// W: L2-resident coalesced 1024B frag loads, 1 step (~258 cyc) ahead.
// MFMA 32x32x16: C/D col(pos)=lane&31, row(o)=(r&3)+8*(r>>2)+4*(lane>>5).
// ---------------------------------------------------------------------------
__global__ __launch_bounds__(256, 3) void conv_main_kernel(const float* __restrict__ x,
                                                           const bf16_t* __restrict__ wt2,
                                                           float* __restrict__ out) {
  __shared__ __align__(16) char xs[192 * 256];   // 49,152 B

  const int tid = threadIdx.x;
  const int lane = tid & 63;
  const int l31 = lane & 31;
  const int lhi = lane >> 5;
  const int wid = tid >> 6;              // 0..3
  const int b = blockIdx.y;
  const int i0 = blockIdx.x;             // 0..61

  const char* wt2b = (const char*)wt2;

  f32x16 acc[2][2];
#pragma unroll
  for (int m = 0; m < 2; ++m)
#pragma unroll
    for (int n = 0; n < 2; ++n)
#pragma unroll
      for (int r = 0; r < 16; ++r) acc[m][n][r] = 0.f;

  // ---- stage: h-rows i0..i0+2, 64 w, 128 c.  thread = (c8, wq) ----
  {
    const int c8 = tid & 15;             // c-octet 0..15
    const int wq = tid >> 4;             // 0..15
#pragma unroll
    for (int h = 0; h < 3; ++h) {
      const float* src = x + (((size_t)b * CIN + c8 * 8) * HIN + (i0 + h)) * WIN + wq * 4;
      f32x4v xr[8];
#pragma unroll
      for (int dc = 0; dc < 8; ++dc)
        xr[dc] = *(const f32x4v*)(src + (size_t)dc * (HIN * WIN));
#pragma unroll
      for (int dw = 0; dw < 4; ++dw) {
        bf16x8 v;
#pragma unroll
        for (int dc = 0; dc < 8; ++dc) v[dc] = (bf16_t)xr[dc][dw];
        int row = h * 64 + wq * 4 + dw;
        *(bf16x8*)(xs + row * 256 + ((c8 * 16) ^ ((row & 15) << 4))) = v;
      }
    }
  }
  __syncthreads();   // the only barrier

  // step s = tap*4 + kkp : tap 0..8, kkp 0..3 (kk pair {2kkp, 2kkp+1})
#define LOAD_A2(dst, s)                                                        \
  {                                                                            \
    const int tap_ = (s) >> 2, kkp_ = (s) & 3;                                 \
    _Pragma("unroll") for (int m = 0; m < 2; ++m)                              \
        _Pragma("unroll") for (int k2 = 0; k2 < 2; ++k2)                       \
            dst[m * 2 + k2] = *(const bf16x8*)(                                \
                wt2b + ((((size_t)tap_ * 8 + wid * 2 + m) * 8 + kkp_ * 2 +     \
                         k2) * 64 + lane) * 16);                               \
  }

#define LOAD_B2(dst, s)                                                        \
  {                                                                            \
    const int tap_ = (s) >> 2, kkp_ = (s) & 3;                                 \
    const int kh_ = tap_ / 3, kw_ = tap_ % 3;                                  \
    _Pragma("unroll") for (int n = 0; n < 2; ++n) {                            \
      int row = kh_ * 64 + n * 32 + l31 + kw_;                                 \
      row = row < 192 ? row : 191;  /* only masked (j>=62) lanes clamp */      \
      _Pragma("unroll") for (int k2 = 0; k2 < 2; ++k2)                         \
          dst[n * 2 + k2] = *(const bf16x8*)(                                  \
              xs + row * 256 +                                                 \
              ((((kkp_ * 2 + k2) * 32) + lhi * 16) ^ ((row & 15) << 4)));      \
    }                                                                          \
  }

#define COMP8(A, B)                                                            \
  {                                                                            \
    __builtin_amdgcn_s_setprio(1);                                             \
    _Pragma("unroll") for (int k2 = 0; k2 < 2; ++k2)                           \
        _Pragma("unroll") for (int n = 0; n < 2; ++n)                          \
            _Pragma("unroll") for (int m = 0; m < 2; ++m)                      \
                acc[m][n] = __builtin_amdgcn_mfma_f32_32x32x16_bf16(           \
                    A[m * 2 + k2], B[n * 2 + k2], acc[m][n], 0, 0, 0);         \
    __builtin_amdgcn_s_setprio(0);                                             \
  }

  bf16x8 Aa[4], Ab[4], Ba[4], Bb[4];
  LOAD_A2(Aa, 0);
  LOAD_B2(Ba, 0);
#pragma unroll
  for (int s = 0; s < 36; s += 2) {
    LOAD_A2(Ab, s + 1);
    LOAD_B2(Bb, s + 1);
    COMP8(Aa, Ba);
    if (s + 2 < 36) {
      LOAD_A2(Aa, s + 2);
      LOAD_B2(Ba, s + 2);
    }
    COMP8(Ab, Bb);
  }

  // ---- epilogue: out[b][o][i0][j] ----
#pragma unroll
  for (int n = 0; n < 2; ++n) {
    int j = n * 32 + l31;
    if (j < 62) {
#pragma unroll
      for (int m = 0; m < 2; ++m) {
#pragma unroll
        for (int r = 0; r < 16; ++r) {
          int o = (wid * 2 + m) * 32 + (r & 3) + 8 * (r >> 2) + 4 * lhi;
          out[((size_t)(b * 256 + o) * OHW + i0) * OHW + j] = acc[m][n][r];
        }
      }
    }
  }
#undef LOAD_A2
#undef LOAD_B2
#undef COMP8
}

// ---------------------------------------------------------------------------
extern "C" void kernel_launch(void* const* d_in, const int* in_sizes, int n_in,
                              void* d_out, int out_size, void* d_ws, size_t ws_size,
                              hipStream_t stream) {
  const float* x = (const float*)d_in[0];
  const float* w = (const float*)d_in[1];
  float* out = (float*)d_out;

  bf16_t* wt2 = (bf16_t*)d_ws;   // 36864 * 16 B = 589,824 B

  conv_wt_kernel<<<dim3(144), dim3(256), 0, stream>>>(w, wt2);
  conv_main_kernel<<<dim3(62, NB), dim3(256), 0, stream>>>(x, wt2, out);
}